// Round 2
// baseline (2393.466 us; speedup 1.0000x reference)
//
#include <hip/hip_runtime.h>
#include <math.h>

// ---------------- problem constants ----------------
#define NROWS   16384      // batch N
#define INF     4096
#define OUTF    4096
#define RANK    409
#define RANK_P  512        // padded rank (zeros beyond 409)
#define NB      683        // ceil(4096/6) blocks per dim
#define NBLK2   (683*683)  // 466489
#define TOPK    46649      // ceil(466489*0.1)
#define SELGRID 1823       // ceil(NBLK2/256)

typedef unsigned short u16;
typedef unsigned int   u32;
typedef unsigned long long u64;

typedef __bf16 v8bf __attribute__((ext_vector_type(8)));
typedef float  v4f  __attribute__((ext_vector_type(4)));

struct SelState { u64 prefix; u64 T; u32 kremain; };

// RNE float -> bf16 (finite inputs)
static __device__ __forceinline__ u16 f2bf(float f) {
    u32 u = __float_as_uint(f);
    u = (u + 0x7FFFu + ((u >> 16) & 1u)) >> 16;
    return (u16)u;
}

static __device__ __forceinline__ void gld_lds16(const void* g, void* l) {
    __builtin_amdgcn_global_load_lds((const __attribute__((address_space(1))) void*)g,
                                     (__attribute__((address_space(3))) void*)l,
                                     16, 0, 0);
}

// ---------------- mask pipeline ----------------

// One workgroup per bo (output-block column). pooled index: bo*683 + bi (fp64,
// deterministic order => exact match of the reference's top-k ordering).
__global__ __launch_bounds__(256) void pooled_kernel(const float* __restrict__ W,
                                                     double* __restrict__ pooled) {
    __shared__ double colsum[INF];
    int bo = blockIdx.x;
    int o0 = bo * 6;
    int cc = min(6, OUTF - o0);
    int tid = threadIdx.x;
    for (int j = tid; j < INF; j += 256) {
        double s = 0.0;
        for (int d = 0; d < cc; d++)
            s += fabs((double)W[(size_t)(o0 + d) * INF + j]);
        colsum[j] = s;
    }
    __syncthreads();
    for (int bi = tid; bi < NB; bi += 256) {
        int i0 = bi * 6;
        int rc = min(6, INF - i0);
        double s = 0.0;
        for (int d = 0; d < rc; d++) s += colsum[i0 + d];
        pooled[(size_t)bo * NB + bi] = s / (double)(rc * cc);
    }
}

__global__ void init_select(u32* hist, u32* counter, SelState* st) {
    int t = blockIdx.x * 256 + threadIdx.x;
    if (t < 2048) hist[t] = 0;
    if (t == 0) { *counter = 0; st->prefix = 0ull; st->T = 0ull; st->kremain = TOPK; }
}

// Fused radix-select pass: per-block LDS histogram -> global hist (atomics) ->
// last-arriving block does a parallel suffix-scan, updates SelState, resets
// hist+counter for the next pass. u64 compare == double compare (all positive).
__global__ __launch_bounds__(256) void select_pass(const double* __restrict__ pooled,
                                                   u32* __restrict__ hist,
                                                   u32* __restrict__ counter,
                                                   SelState* __restrict__ st,
                                                   int shift, int hs, int width,
                                                   int nbins, int pass, int is_last) {
    __shared__ u32 h[2048];
    __shared__ u32 sc[256];
    __shared__ int s_flag;
    __shared__ int s_cand;
    int tid = threadIdx.x;
    for (int i = tid; i < nbins; i += 256) h[i] = 0;
    __syncthreads();
    int idx = blockIdx.x * 256 + tid;
    if (idx < NBLK2) {
        u64 bits = (u64)__double_as_longlong(pooled[idx]);
        bool ok = (pass == 0) || ((bits >> hs) == st->prefix);
        if (ok) atomicAdd(&h[(u32)((bits >> shift) & (u64)(nbins - 1))], 1u);
    }
    __syncthreads();
    for (int i = tid; i < nbins; i += 256)
        if (h[i]) atomicAdd(&hist[i], h[i]);
    __threadfence();
    if (tid == 0) {
        u32 old = atomicAdd(counter, 1u);
        s_flag = (old == (u32)(gridDim.x - 1)) ? 1 : 0;
    }
    __syncthreads();
    if (!s_flag) return;

    // ---- finalizer (one block) ----
    for (int i = tid; i < nbins; i += 256) h[i] = atomicAdd(&hist[i], 0u);
    __syncthreads();
    int bpt = nbins >> 8;             // bins per thread (8 or 2)
    int base = tid * bpt;
    u32 partial = 0;
    for (int b = 0; b < bpt; b++) partial += h[base + b];
    sc[tid] = partial;
    __syncthreads();
    for (int off = 1; off < 256; off <<= 1) {       // suffix-inclusive scan
        u32 v = (tid + off < 256) ? sc[tid + off] : 0u;
        __syncthreads();
        sc[tid] += v;
        __syncthreads();
    }
    u32 kr = st->kremain;
    if (tid == 0) s_cand = -1;
    __syncthreads();
    u32 run = (tid + 1 < 256) ? sc[tid + 1] : 0u;   // sum of bins above my range
    int my_d = -1; u32 my_above = 0;
    for (int b = bpt - 1; b >= 0; b--) {
        int d = base + b;
        u32 nrun = run + h[d];
        if (my_d < 0 && nrun >= kr) { my_d = d; my_above = run; }
        run = nrun;
    }
    if (my_d >= 0) atomicMax(&s_cand, my_d);
    __syncthreads();
    if (my_d >= 0 && my_d == s_cand) {
        u64 np = (st->prefix << width) | (u64)my_d;
        st->prefix = np;
        st->kremain = kr - my_above;
        if (is_last) st->T = np;
    }
    __syncthreads();
    for (int i = tid; i < nbins; i += 256) hist[i] = 0;
    if (tid == 0) *counter = 0;
}

// Masked weight -> bf16, row-major (o, i). flag = pooled(bi,bo) >= T
__global__ __launch_bounds__(256) void build_wmb(const float* __restrict__ W,
                                                 const double* __restrict__ pooled,
                                                 const SelState* __restrict__ st,
                                                 u16* __restrict__ wmb) {
    size_t idx = ((size_t)blockIdx.x * 256 + threadIdx.x) * 4;
    int o = (int)(idx >> 12);
    int i = (int)(idx & 4095);
    float4 w = *(const float4*)(W + idx);
    u64 T = st->T;
    int bo = o / 6;
    float wv[4] = {w.x, w.y, w.z, w.w};
    u16 rr[4];
#pragma unroll
    for (int e = 0; e < 4; e++) {
        int bi = (i + e) / 6;
        u64 b = (u64)__double_as_longlong(pooled[(size_t)bo * NB + bi]);
        rr[e] = (b >= T) ? f2bf(wv[e]) : (u16)0;
    }
    ushort4 r; r.x = rr[0]; r.y = rr[1]; r.z = rr[2]; r.w = rr[3];
    *(ushort4*)(wmb + idx) = r;
}

// ---------------- gate + scaled bf16 packs of x ----------------
// XBG = bf16(g*x), XM = bf16((1-g)*x), G[row] = g
__global__ __launch_bounds__(256) void gate_xb2(const float* __restrict__ X,
                                                const float* __restrict__ gw,
                                                const float* __restrict__ gb,
                                                u16* __restrict__ XBG,
                                                u16* __restrict__ XM,
                                                float* __restrict__ G) {
    __shared__ float red[256];
    int row = blockIdx.x, tid = threadIdx.x;
    const float* xr = X + (size_t)row * INF;
    float4 v[4];
    float dot = 0.f;
#pragma unroll
    for (int jj = 0; jj < 4; jj++) {
        int col = jj * 1024 + tid * 4;
        v[jj] = *(const float4*)(xr + col);
        float4 w = *(const float4*)(gw + col);
        dot += v[jj].x * w.x + v[jj].y * w.y + v[jj].z * w.z + v[jj].w * w.w;
    }
    red[tid] = dot;
    __syncthreads();
    for (int s = 128; s > 0; s >>= 1) {
        if (tid < s) red[tid] += red[tid + s];
        __syncthreads();
    }
    float g = 1.f / (1.f + expf(-(red[0] + gb[0])));
    float h = 1.f - g;
#pragma unroll
    for (int jj = 0; jj < 4; jj++) {
        int col = jj * 1024 + tid * 4;
        ushort4 a, b;
        a.x = f2bf(g * v[jj].x); a.y = f2bf(g * v[jj].y);
        a.z = f2bf(g * v[jj].z); a.w = f2bf(g * v[jj].w);
        b.x = f2bf(h * v[jj].x); b.y = f2bf(h * v[jj].y);
        b.z = f2bf(h * v[jj].z); b.w = f2bf(h * v[jj].w);
        *(ushort4*)(XBG + (size_t)row * INF + col) = a;
        *(ushort4*)(XM  + (size_t)row * INF + col) = b;
    }
    if (tid == 0) G[row] = g;
}

// ---------------- transpose+pack fp32 -> bf16, zero-pad ----------------
__global__ void transpose_pack(const float* __restrict__ src, u16* __restrict__ dst,
                               int sr, int sc_, int dr, int dc) {
    __shared__ float tile[32][33];
    int i0 = blockIdx.x * 32;
    int j0 = blockIdx.y * 32;
    for (int yy = threadIdx.y; yy < 32; yy += 8) {
        int si = i0 + yy, sj = j0 + threadIdx.x;
        tile[yy][threadIdx.x] = (si < sr && sj < sc_) ? src[(size_t)si * sc_ + sj] : 0.f;
    }
    __syncthreads();
    for (int yy = threadIdx.y; yy < 32; yy += 8) {
        int dj = j0 + yy, di = i0 + threadIdx.x;
        if (dj < dr && di < dc) dst[(size_t)dj * dc + di] = f2bf(tile[threadIdx.x][yy]);
    }
}

// ---------------- swizzled MFMA K-loop phase ----------------
// LDS layout: slot s (16B) holds global chunk ((s&3) ^ ((s>>3)&3)) of row s>>2.
// Reader for row r, K-chunk q reads slot r*4 + (q ^ ((r>>1)&3)) -> all 8 LDS
// bank-groups hit 2-way per quarter-wave (conflict-free, m136).
static __device__ __forceinline__ void mma_phase(const u16* __restrict__ Ab,
                                                 const u16* __restrict__ Bb, int K,
                                                 u16* As, u16* Bs, v4f (&acc)[4][4],
                                                 int rA0, int e0,
                                                 char* lA0, char* lA1, char* lB0, char* lB1,
                                                 int wm, int wn, int lrow, int xq) {
    for (int k0 = 0; k0 < K; k0 += 32) {
        __syncthreads();
        gld_lds16(Ab + (size_t)rA0 * K + k0 + e0, lA0);
        gld_lds16(Ab + (size_t)(rA0 + 64) * K + k0 + e0, lA1);
        gld_lds16(Bb + (size_t)rA0 * K + k0 + e0, lB0);
        gld_lds16(Bb + (size_t)(rA0 + 64) * K + k0 + e0, lB1);
        __syncthreads();
        v8bf af[4], bfv[4];
#pragma unroll
        for (int i = 0; i < 4; i++)
            af[i] = *(const v8bf*)(As + (wm * 64 + i * 16 + lrow) * 32 + xq * 8);
#pragma unroll
        for (int j = 0; j < 4; j++)
            bfv[j] = *(const v8bf*)(Bs + (wn * 64 + j * 16 + lrow) * 32 + xq * 8);
#pragma unroll
        for (int i = 0; i < 4; i++)
#pragma unroll
            for (int j = 0; j < 4; j++)
                acc[i][j] = __builtin_amdgcn_mfma_f32_16x16x32_bf16(af[i], bfv[j], acc[i][j], 0, 0, 0);
    }
}

// ---------------- gemm_lr: Tbuf = bf16( ((1-g)x) @ lr1 ), N=512 ----------------
__global__ __launch_bounds__(256) void gemm_lr(const u16* __restrict__ A,
                                               const u16* __restrict__ B,
                                               u16* __restrict__ TOUT) {
    __shared__ __align__(16) u16 As[128 * 32];
    __shared__ __align__(16) u16 Bs[128 * 32];
    int tid = threadIdx.x, wave = tid >> 6, lane = tid & 63;
    int quad = lane >> 4, lrow = lane & 15;
    int wm = wave >> 1, wn = wave & 1;
    int m0 = blockIdx.y * 128, n0 = blockIdx.x * 128;
    int xq = quad ^ ((lrow >> 1) & 3);
    int rA0 = tid >> 2;
    int e0 = (((tid & 3) ^ ((tid >> 3) & 3))) * 8;
    char* lA0 = (char*)As + (size_t)(wave * 64) * 16;
    char* lA1 = (char*)As + (size_t)(wave * 64 + 256) * 16;
    char* lB0 = (char*)Bs + (size_t)(wave * 64) * 16;
    char* lB1 = (char*)Bs + (size_t)(wave * 64 + 256) * 16;

    v4f acc[4][4];
#pragma unroll
    for (int i = 0; i < 4; i++)
#pragma unroll
        for (int j = 0; j < 4; j++) acc[i][j] = (v4f)0.f;

    mma_phase(A + (size_t)m0 * INF, B + (size_t)n0 * INF, INF,
              As, Bs, acc, rA0, e0, lA0, lA1, lB0, lB1, wm, wn, lrow, xq);

#pragma unroll
    for (int i = 0; i < 4; i++)
#pragma unroll
        for (int r = 0; r < 4; r++) {
            int grow = m0 + wm * 64 + i * 16 + quad * 4 + r;
#pragma unroll
            for (int j = 0; j < 4; j++) {
                int gcol = n0 + wn * 64 + j * 16 + lrow;
                TOUT[(size_t)grow * RANK_P + gcol] = f2bf(acc[i][j][r]);
            }
        }
}

// ---------------- gemm_final: OUT = XBG@WMB^T + TB@L2T^T + g*SB + (1-g)*LB ----
__global__ __launch_bounds__(256) void gemm_final(const u16* __restrict__ XBG,
                                                  const u16* __restrict__ WMB,
                                                  const u16* __restrict__ TB,
                                                  const u16* __restrict__ L2T,
                                                  float* __restrict__ OUT,
                                                  const float* __restrict__ G,
                                                  const float* __restrict__ SB,
                                                  const float* __restrict__ LB) {
    __shared__ __align__(16) u16 As[128 * 32];
    __shared__ __align__(16) u16 Bs[128 * 32];
    int tid = threadIdx.x, wave = tid >> 6, lane = tid & 63;
    int quad = lane >> 4, lrow = lane & 15;
    int wm = wave >> 1, wn = wave & 1;
    // XCD-aware swizzle: blocks round-robin XCDs by linear id (m09); give each
    // XCD a 4-wide bx stripe so its 4MB L2 holds the B working set.
    int lin = blockIdx.y * gridDim.x + blockIdx.x;
    int xcd = lin & 7, slot = lin >> 3;
    int bx = xcd * 4 + (slot & 3);
    int by = slot >> 2;
    int m0 = by * 128, n0 = bx * 128;
    int xq = quad ^ ((lrow >> 1) & 3);
    int rA0 = tid >> 2;
    int e0 = (((tid & 3) ^ ((tid >> 3) & 3))) * 8;
    char* lA0 = (char*)As + (size_t)(wave * 64) * 16;
    char* lA1 = (char*)As + (size_t)(wave * 64 + 256) * 16;
    char* lB0 = (char*)Bs + (size_t)(wave * 64) * 16;
    char* lB1 = (char*)Bs + (size_t)(wave * 64 + 256) * 16;

    v4f acc[4][4];
#pragma unroll
    for (int i = 0; i < 4; i++)
#pragma unroll
        for (int j = 0; j < 4; j++) acc[i][j] = (v4f)0.f;

    // phase 1: sparse branch (K=4096)
    mma_phase(XBG + (size_t)m0 * INF, WMB + (size_t)n0 * INF, INF,
              As, Bs, acc, rA0, e0, lA0, lA1, lB0, lB1, wm, wn, lrow, xq);
    // phase 2: low-rank tail (K=512) into the SAME accumulator
    mma_phase(TB + (size_t)m0 * RANK_P, L2T + (size_t)n0 * RANK_P, RANK_P,
              As, Bs, acc, rA0, e0, lA0, lA1, lB0, lB1, wm, wn, lrow, xq);

#pragma unroll
    for (int i = 0; i < 4; i++)
#pragma unroll
        for (int r = 0; r < 4; r++) {
            int grow = m0 + wm * 64 + i * 16 + quad * 4 + r;
            float gv = G[grow];
#pragma unroll
            for (int j = 0; j < 4; j++) {
                int gcol = n0 + wn * 64 + j * 16 + lrow;
                OUT[(size_t)grow * OUTF + gcol] =
                    acc[i][j][r] + gv * SB[gcol] + (1.f - gv) * LB[gcol];
            }
        }
}

// ---------------- launcher ----------------
extern "C" void kernel_launch(void* const* d_in, const int* in_sizes, int n_in,
                              void* d_out, int out_size, void* d_ws, size_t ws_size,
                              hipStream_t stream) {
    const float* X   = (const float*)d_in[0];   // (16384, 4096)
    const float* GW  = (const float*)d_in[1];   // (4096, 1)
    const float* GB  = (const float*)d_in[2];   // (1,)
    const float* W   = (const float*)d_in[3];   // (4096, 4096)
    const float* SBv = (const float*)d_in[4];   // (4096,)
    const float* LR1 = (const float*)d_in[5];   // (4096, 409)
    const float* LR2 = (const float*)d_in[6];   // (409, 4096)
    const float* LBv = (const float*)d_in[7];   // (4096,)
    float* OUT = (float*)d_out;

    // workspace layout (bytes)
    const size_t OFF_POOLED = 0;                                   // 3.73 MB
    const size_t OFF_HIST   = 4ull << 20;
    const size_t OFF_CNT    = OFF_HIST + 2048 * 4;
    const size_t OFF_STATE  = OFF_CNT + 64;
    const size_t OFF_XBG    = 8ull << 20;                          // 128 MB
    const size_t OFF_WMB    = OFF_XBG + (size_t)NROWS * INF * 2;   // 32 MB
    const size_t OFF_LR1T   = OFF_WMB + (size_t)OUTF * INF * 2;    // 4 MB
    const size_t OFF_LR2T   = OFF_LR1T + (size_t)RANK_P * INF * 2; // 4 MB
    const size_t OFF_TB     = OFF_LR2T + (size_t)OUTF * RANK_P * 2;// 16 MB
    const size_t OFF_G      = OFF_TB + (size_t)NROWS * RANK_P * 2;
    const size_t NEED       = OFF_G + (size_t)NROWS * 4;
    if (ws_size < NEED) return;  // visible failure (poison retained)

    char* ws = (char*)d_ws;
    double*   pooled = (double*)(ws + OFF_POOLED);
    u32*      hist   = (u32*)(ws + OFF_HIST);
    u32*      cnt    = (u32*)(ws + OFF_CNT);
    SelState* st     = (SelState*)(ws + OFF_STATE);
    u16*      XBG    = (u16*)(ws + OFF_XBG);
    u16*      WMB    = (u16*)(ws + OFF_WMB);
    u16*      LR1T   = (u16*)(ws + OFF_LR1T);
    u16*      LR2T   = (u16*)(ws + OFF_LR2T);
    u16*      TB     = (u16*)(ws + OFF_TB);
    float*    G      = (float*)(ws + OFF_G);
    u16*      XM     = (u16*)d_out;  // (1-g)x staged in d_out; dead before gemm_final writes

    // 1) gate + scaled packs (independent of mask)
    gate_xb2<<<NROWS, 256, 0, stream>>>(X, GW, GB, XBG, XM, G);

    // 2) pooled block means (fp64, deterministic)
    pooled_kernel<<<NB, 256, 0, stream>>>(W, pooled);

    // 3) exact 64-bit radix select (6 fused passes)
    init_select<<<8, 256, 0, stream>>>(hist, cnt, st);
    const int sh[6] = {53, 42, 31, 20, 9, 0};
    const int wd[6] = {11, 11, 11, 11, 11, 9};
    for (int p = 0; p < 6; p++) {
        int nb = 1 << wd[p];
        select_pass<<<SELGRID, 256, 0, stream>>>(pooled, hist, cnt, st,
                                                 sh[p], sh[p] + wd[p], wd[p], nb, p,
                                                 (p == 5) ? 1 : 0);
    }

    // 4) packs
    build_wmb<<<(OUTF * INF) / (256 * 4), 256, 0, stream>>>(W, pooled, st, WMB);
    {
        dim3 b(32, 8);
        transpose_pack<<<dim3(INF / 32, RANK_P / 32), b, 0, stream>>>(LR1, LR1T, INF, RANK, RANK_P, INF);
        transpose_pack<<<dim3(RANK_P / 32, OUTF / 32), b, 0, stream>>>(LR2, LR2T, RANK, OUTF, OUTF, RANK_P);
    }

    // 5) GEMMs
    gemm_lr<<<dim3(RANK_P / 128, NROWS / 128), 256, 0, stream>>>(XM, LR1T, TB);
    gemm_final<<<dim3(OUTF / 128, NROWS / 128), 256, 0, stream>>>(
        XBG, WMB, TB, LR2T, OUT, G, SBv, LBv);
}